// Round 1
// baseline (367.707 us; speedup 1.0000x reference)
//
#include <hip/hip_runtime.h>
#include <hip/hip_bf16.h>

typedef __attribute__((ext_vector_type(8))) short bf16x8;
typedef __attribute__((ext_vector_type(4))) float f32x4;

#define N_OUT 65536
#define CIN   256
#define COUT  512
#define KDIM  2048
#define BM    128
#define BK    32
#define NKB   64    // KDIM/BK

__device__ __forceinline__ unsigned short f2bf(float f) {
  union { __hip_bfloat16 h; unsigned short u; } c;
  c.h = __float2bfloat16(f);
  return c.u;
}

// --- weight prep: W[k][n] f32 (row-major) -> Wt tiled bf16:
//     Wt[kb*16384 + n*32 + kk] = bf16(W[kb*32+kk][n]),  kb in [0,64), n in [0,512), kk in [0,32)
__global__ void wprep_kernel(const float* __restrict__ W, unsigned short* __restrict__ Wt) {
  int idx = blockIdx.x * blockDim.x + threadIdx.x;   // 131072 threads, 8 elems each
  if (idx >= 64 * 4 * COUT) return;
  int n  = idx & (COUT - 1);
  int s  = (idx >> 9) & 3;       // which group of 8 k's
  int kb = idx >> 11;
  unsigned short tmp[8];
#pragma unroll
  for (int w = 0; w < 8; ++w)
    tmp[w] = f2bf(W[(size_t)(kb * 32 + s * 8 + w) * COUT + n]);   // coalesced over n
  *reinterpret_cast<bf16x8*>(Wt + ((size_t)kb * 16384 + n * 32 + s * 8)) =
      *reinterpret_cast<bf16x8*>(tmp);
}

// --- main GEMM: out_raw = gather(data,neigh) @ Wt   (+ per-block column partial sums)
__global__ __launch_bounds__(512, 2) void gemm_kernel(
    const float* __restrict__ data,        // [N_in][256] f32
    const int*   __restrict__ neigh,       // [N_out][8] i32
    const unsigned short* __restrict__ Wt, // tiled bf16 [64][512][32]
    float* __restrict__ out,               // [N_out][512] raw (pre-BN)
    float* __restrict__ psum,              // [512 blocks][512] col sums
    float* __restrict__ psq)               // [512 blocks][512] col sumsq
{
  __shared__ union {
    unsigned short as[2][BM * BK];   // 2 x 8KB, swizzled
    float st[4][COUT];               // stats overlay: [wr][c] sums, [2+wr][c] sumsq
  } sm;

  const int tid = threadIdx.x;
  const int l   = tid & 63;
  const int w   = tid >> 6;         // 8 waves
  const int wr  = w >> 2;           // 0..1  (64-row strip)
  const int wc  = w & 3;            // 0..3  (128-col strip)
  const int lg  = l >> 4;
  const int lm  = l & 15;
  const int m0  = blockIdx.x * BM;

  // A staging assignment: thread -> (row, 8-float chunk)
  const int arow = tid >> 2;                          // 0..127
  const int aqc  = tid & 3;                           // 0..3
  const int aswz = (aqc ^ ((arow >> 1) & 3)) << 3;    // swizzled 8-elem slot

  f32x4 acc[4][8];
#pragma unroll
  for (int i = 0; i < 4; ++i)
#pragma unroll
    for (int j = 0; j < 8; ++j) acc[i][j] = (f32x4){0.f, 0.f, 0.f, 0.f};

  int gA; f32x4 a0, a1;
  bf16x8 af[4], bfA[8], bfB[8];

#define STAGE_LOAD(kb) do { \
    gA = neigh[(size_t)(m0 + arow) * 8 + ((kb) >> 3)]; \
    const float* asrc = data + (size_t)gA * CIN + (((kb) & 7) * 32 + aqc * 8); \
    a0 = *reinterpret_cast<const f32x4*>(asrc); \
    a1 = *reinterpret_cast<const f32x4*>(asrc + 4); \
  } while (0)

#define STAGE_WRITE(buf) do { \
    unsigned short us[8]; \
    us[0]=f2bf(a0.x); us[1]=f2bf(a0.y); us[2]=f2bf(a0.z); us[3]=f2bf(a0.w); \
    us[4]=f2bf(a1.x); us[5]=f2bf(a1.y); us[6]=f2bf(a1.z); us[7]=f2bf(a1.w); \
    *reinterpret_cast<bf16x8*>(&sm.as[buf][arow * 32 + aswz]) = *reinterpret_cast<bf16x8*>(us); \
  } while (0)

#define LOAD_B(kb, bf) do { \
    const unsigned short* wt = Wt + (size_t)(kb) * 16384 + wc * 4096 + lm * 32 + lg * 8; \
    _Pragma("unroll") \
    for (int ni = 0; ni < 8; ++ni) bf[ni] = *reinterpret_cast<const bf16x8*>(wt + ni * 512); \
  } while (0)

#define LOAD_AF(buf) do { \
    _Pragma("unroll") \
    for (int mi = 0; mi < 4; ++mi) { \
      int row = wr * 64 + mi * 16 + lm; \
      af[mi] = *reinterpret_cast<const bf16x8*>( \
          &sm.as[buf][row * 32 + ((lg ^ ((row >> 1) & 3)) << 3)]); \
    } \
  } while (0)

#define DO_MFMA(bf) do { \
    _Pragma("unroll") \
    for (int mi = 0; mi < 4; ++mi) \
      _Pragma("unroll") \
      for (int ni = 0; ni < 8; ++ni) \
        acc[mi][ni] = __builtin_amdgcn_mfma_f32_16x16x32_bf16(af[mi], bf[ni], acc[mi][ni], 0, 0, 0); \
  } while (0)

  // prologue: tile 0
  STAGE_LOAD(0);
  LOAD_B(0, bfA);
  STAGE_WRITE(0);
  __syncthreads();

  for (int kb = 0; kb < NKB; kb += 2) {
    // even step: compute from As[0]/bfA, stage kb+1 into As[1]/bfB
    STAGE_LOAD(kb + 1);
    LOAD_B(kb + 1, bfB);
    LOAD_AF(0);
    DO_MFMA(bfA);
    STAGE_WRITE(1);
    __syncthreads();

    // odd step: compute from As[1]/bfB, stage kb+2 into As[0]/bfA
    if (kb + 2 < NKB) {
      STAGE_LOAD(kb + 2);
      LOAD_B(kb + 2, bfA);
    }
    LOAD_AF(1);
    DO_MFMA(bfB);
    if (kb + 2 < NKB) STAGE_WRITE(0);
    __syncthreads();
  }

  // epilogue 1: raw out write (C layout: col = lane&15, row = (lane>>4)*4 + reg)
#pragma unroll
  for (int mi = 0; mi < 4; ++mi) {
#pragma unroll
    for (int r = 0; r < 4; ++r) {
      size_t row = (size_t)(m0 + wr * 64 + mi * 16 + lg * 4 + r);
      float* op = out + row * COUT + wc * 128 + lm;
#pragma unroll
      for (int ni = 0; ni < 8; ++ni) op[ni * 16] = acc[mi][ni][r];
    }
  }

  // epilogue 2: per-block column sums / sumsq (deterministic; no atomics)
#pragma unroll
  for (int ni = 0; ni < 8; ++ni) {
    float s1 = 0.f, s2 = 0.f;
#pragma unroll
    for (int mi = 0; mi < 4; ++mi)
#pragma unroll
      for (int r = 0; r < 4; ++r) { float v = acc[mi][ni][r]; s1 += v; s2 += v * v; }
    s1 += __shfl_xor(s1, 16, 64); s1 += __shfl_xor(s1, 32, 64);
    s2 += __shfl_xor(s2, 16, 64); s2 += __shfl_xor(s2, 32, 64);
    if (l < 16) {
      sm.st[wr][wc * 128 + ni * 16 + l]     = s1;
      sm.st[2 + wr][wc * 128 + ni * 16 + l] = s2;
    }
  }
  __syncthreads();
  {
    float S = sm.st[0][tid] + sm.st[1][tid];
    float Q = sm.st[2][tid] + sm.st[3][tid];
    psum[(size_t)blockIdx.x * COUT + tid] = S;
    psq [(size_t)blockIdx.x * COUT + tid] = Q;
  }
#undef STAGE_LOAD
#undef STAGE_WRITE
#undef LOAD_B
#undef LOAD_AF
#undef DO_MFMA
}

// --- stats reduction, stage 1: 512 -> 64 partials per column
__global__ void reduce1_kernel(const float* __restrict__ psum, const float* __restrict__ psq,
                               float* __restrict__ p2) {
  int c = threadIdx.x, b = blockIdx.x;
  float s = 0.f, q = 0.f;
#pragma unroll
  for (int j = 0; j < 8; ++j) {
    s += psum[(size_t)(b * 8 + j) * COUT + c];
    q += psq [(size_t)(b * 8 + j) * COUT + c];
  }
  p2[b * 1024 + c] = s;
  p2[b * 1024 + 512 + c] = q;
}

// --- stats reduction, stage 2: final mean/var -> per-column scale/shift
__global__ void reduce2_kernel(const float* __restrict__ p2,
                               const float* __restrict__ gamma,
                               const float* __restrict__ beta,
                               float* __restrict__ scsh) {
  int c = threadIdx.x;
  float s = 0.f, q = 0.f;
  for (int b = 0; b < 64; ++b) { s += p2[b * 1024 + c]; q += p2[b * 1024 + 512 + c]; }
  float mean = s * (1.f / 65536.f);
  float var  = q * (1.f / 65536.f) - mean * mean;
  float rs   = rsqrtf(var + 1e-5f);
  float sc   = gamma[c] * rs;
  scsh[c] = sc;
  scsh[COUT + c] = beta[c] - mean * sc;   // bias cancels in BN, omitted by design
}

// --- apply BN in-place on out
__global__ void bn_kernel(float* __restrict__ out, const float* __restrict__ scsh) {
  __shared__ float sc[COUT], sh[COUT];
  int t = threadIdx.x;
  sc[t] = scsh[t];
  sh[t] = scsh[COUT + t];
  __syncthreads();
  f32x4* o4 = reinterpret_cast<f32x4*>(out);
  const size_t total  = (size_t)N_OUT * COUT / 4;
  const size_t stride = (size_t)gridDim.x * blockDim.x;
  for (size_t i = (size_t)blockIdx.x * blockDim.x + t; i < total; i += stride) {
    f32x4 v = o4[i];
    int c = ((int)(i & 127)) * 4;      // 128 float4 per 512-col row
    v.x = v.x * sc[c]     + sh[c];
    v.y = v.y * sc[c + 1] + sh[c + 1];
    v.z = v.z * sc[c + 2] + sh[c + 2];
    v.w = v.w * sc[c + 3] + sh[c + 3];
    o4[i] = v;
  }
}

extern "C" void kernel_launch(void* const* d_in, const int* in_sizes, int n_in,
                              void* d_out, int out_size, void* d_ws, size_t ws_size,
                              hipStream_t stream) {
  const float* data   = (const float*)d_in[0];
  const float* weight = (const float*)d_in[1];
  // d_in[2] = bias: provably cancels in BatchNorm (mean absorbs it) -> unused
  const float* gamma  = (const float*)d_in[3];
  const float* beta   = (const float*)d_in[4];
  const int*   neigh  = (const int*)d_in[5];
  float* out = (float*)d_out;

  char* ws = (char*)d_ws;
  unsigned short* Wt = (unsigned short*)ws;                        // 2 MB
  float* psum = (float*)(ws + (2u << 20));                         // 1 MB
  float* psq  = (float*)(ws + (3u << 20));                         // 1 MB
  float* p2   = (float*)(ws + (4u << 20));                         // 256 KB
  float* scsh = (float*)(ws + (4u << 20) + (256u << 10));          // 4 KB

  wprep_kernel<<<512, 256, 0, stream>>>(weight, Wt);
  gemm_kernel<<<N_OUT / BM, 512, 0, stream>>>(data, neigh, Wt, out, psum, psq);
  reduce1_kernel<<<64, 512, 0, stream>>>(psum, psq, p2);
  reduce2_kernel<<<1, 512, 0, stream>>>(p2, gamma, beta, scsh);
  bn_kernel<<<2048, 512, 0, stream>>>(out, scsh);
}